// Round 1
// baseline (650.636 us; speedup 1.0000x reference)
//
#include <hip/hip_runtime.h>
#include <hip/hip_bf16.h>

// Problem constants (reference: WORLD_SIZE=8, M_LOCAL=1024, K=4096, N=4096)
#define M_TOTAL 8192
#define KDIM    4096
#define NDIM    4096

#define TM 128
#define TN 128
#define BK 32

typedef __bf16 bf16x8 __attribute__((ext_vector_type(8)));
typedef float  f32x4  __attribute__((ext_vector_type(4)));

// ---------------------------------------------------------------------------
// fp32 -> bf16 (RNE) convert, 8 elems/thread, fully vectorized (16B ld/st)
// ---------------------------------------------------------------------------
__device__ __forceinline__ unsigned short f32_to_bf16_rne(unsigned u) {
    unsigned r = u + 0x7fffu + ((u >> 16) & 1u);
    return (unsigned short)(r >> 16);
}

__global__ __launch_bounds__(256) void cvt_f32_to_bf16(const float* __restrict__ s,
                                                       unsigned short* __restrict__ d,
                                                       long n) {
    long i = ((long)blockIdx.x * 256 + threadIdx.x) * 8;
    if (i + 8 > n) return;
    const uint4* sp = (const uint4*)(s + i);
    uint4 x = sp[0];
    uint4 y = sp[1];
    uint4 o;
    o.x = (unsigned)f32_to_bf16_rne(x.x) | ((unsigned)f32_to_bf16_rne(x.y) << 16);
    o.y = (unsigned)f32_to_bf16_rne(x.z) | ((unsigned)f32_to_bf16_rne(x.w) << 16);
    o.z = (unsigned)f32_to_bf16_rne(y.x) | ((unsigned)f32_to_bf16_rne(y.y) << 16);
    o.w = (unsigned)f32_to_bf16_rne(y.z) | ((unsigned)f32_to_bf16_rne(y.w) << 16);
    *(uint4*)(d + i) = o;
}

// ---------------------------------------------------------------------------
// async global -> LDS, 16B per lane (wave-uniform LDS base + lane*16)
// ---------------------------------------------------------------------------
__device__ __forceinline__ void gload_lds16(const unsigned short* g, unsigned short* l) {
    __builtin_amdgcn_global_load_lds(
        (const __attribute__((address_space(1))) unsigned int*)g,
        (__attribute__((address_space(3))) unsigned int*)l,
        16, 0, 0);
}

// ---------------------------------------------------------------------------
// C[M,N] = A[M,K] * B[N,K]^T   (bf16 inputs, fp32 out)
// 128x128 tile, BK=32, 256 threads (4 waves, 2x2), 16x16x32 bf16 MFMA
// ---------------------------------------------------------------------------
__global__ __launch_bounds__(256) void gemm_bt(const unsigned short* __restrict__ A,
                                               const unsigned short* __restrict__ B,
                                               float* __restrict__ C) {
    __shared__ unsigned short lA[TM * BK];   // row-major [128][32], 8 KiB
    __shared__ unsigned short lB[TN * BK];   // row-major [128][32], 8 KiB

    const int tid  = threadIdx.x;
    const int wave = tid >> 6;
    const int lane = tid & 63;

    const int n0 = blockIdx.x * TN;
    const int m0 = blockIdx.y * TM;

    // staging: chunk c = wave + 4*j (j=0,1) covers rows [c*16, c*16+16)
    // lane l within chunk: row = c*16 + l/4, k = (l%4)*8  (16B per lane)
    const int row_ic = lane >> 2;        // 0..15
    const int k_ic   = (lane & 3) * 8;   // 0,8,16,24

    const int c0 = wave;
    const int c1 = wave + 4;

    const unsigned short* gA0 = A + (size_t)(m0 + c0 * 16 + row_ic) * KDIM + k_ic;
    const unsigned short* gA1 = A + (size_t)(m0 + c1 * 16 + row_ic) * KDIM + k_ic;
    const unsigned short* gB0 = B + (size_t)(n0 + c0 * 16 + row_ic) * KDIM + k_ic;
    const unsigned short* gB1 = B + (size_t)(n0 + c1 * 16 + row_ic) * KDIM + k_ic;
    unsigned short* lA0 = &lA[c0 * 16 * BK];   // wave-uniform bases
    unsigned short* lA1 = &lA[c1 * 16 * BK];
    unsigned short* lB0 = &lB[c0 * 16 * BK];
    unsigned short* lB1 = &lB[c1 * 16 * BK];

    // wave -> 64x64 quadrant; MFMA fragment indices
    const int wm   = wave & 1;
    const int wn   = wave >> 1;
    const int quad = lane >> 4;    // 0..3  (K-block index for A/B operands)
    const int r    = lane & 15;    // m (A) / n (B) / col (C)

    f32x4 acc[4][4] = {};

    for (int k0 = 0; k0 < KDIM; k0 += BK) {
        gload_lds16(gA0 + k0, lA0);
        gload_lds16(gA1 + k0, lA1);
        gload_lds16(gB0 + k0, lB0);
        gload_lds16(gB1 + k0, lB1);
        __syncthreads();   // drains vmcnt -> staged data visible

        bf16x8 aF[4], bF[4];
#pragma unroll
        for (int mi = 0; mi < 4; ++mi)
            aF[mi] = *(const bf16x8*)&lA[(wm * 64 + mi * 16 + r) * BK + quad * 8];
#pragma unroll
        for (int ni = 0; ni < 4; ++ni)
            bF[ni] = *(const bf16x8*)&lB[(wn * 64 + ni * 16 + r) * BK + quad * 8];

#pragma unroll
        for (int mi = 0; mi < 4; ++mi)
#pragma unroll
            for (int ni = 0; ni < 4; ++ni)
                acc[mi][ni] = __builtin_amdgcn_mfma_f32_16x16x32_bf16(
                    aF[mi], bF[ni], acc[mi][ni], 0, 0, 0);

        __syncthreads();   // all reads done before next stage overwrites
    }

    // epilogue: C/D layout col = lane&15, row = quad*4 + reg  [verified m89/m91]
#pragma unroll
    for (int mi = 0; mi < 4; ++mi) {
        const int row = m0 + wm * 64 + mi * 16 + quad * 4;
#pragma unroll
        for (int ni = 0; ni < 4; ++ni) {
            const int col = n0 + wn * 64 + ni * 16 + r;
            float* p = C + (size_t)row * NDIM + col;
#pragma unroll
            for (int rr = 0; rr < 4; ++rr)
                p[(size_t)rr * NDIM] = acc[mi][ni][rr];
        }
    }
}

// ---------------------------------------------------------------------------
extern "C" void kernel_launch(void* const* d_in, const int* in_sizes, int n_in,
                              void* d_out, int out_size, void* d_ws, size_t ws_size,
                              hipStream_t stream) {
    const float* A = (const float*)d_in[0];   // [8,1024,4096] == [8192,4096]
    const float* W = (const float*)d_in[1];   // [4096,4096]  (N,K)
    float* out = (float*)d_out;               // [8192,4096] fp32

    unsigned short* Abf = (unsigned short*)d_ws;                       // 64 MiB
    unsigned short* Wbf = Abf + (size_t)M_TOTAL * KDIM;                // 32 MiB

    const long nA = (long)M_TOTAL * KDIM;     // 33,554,432
    const long nW = (long)NDIM * KDIM;        // 16,777,216

    cvt_f32_to_bf16<<<(int)(nA / 8 / 256), 256, 0, stream>>>(A, Abf, nA);
    cvt_f32_to_bf16<<<(int)(nW / 8 / 256), 256, 0, stream>>>(W, Wbf, nW);

    dim3 grid(NDIM / TN, M_TOTAL / TM);       // (32, 64) = 2048 blocks
    gemm_bt<<<grid, 256, 0, stream>>>(Abf, Wbf, out);
}

// Round 2
// 636.315 us; speedup vs baseline: 1.0225x; 1.0225x over previous
//
#include <hip/hip_runtime.h>
#include <hip/hip_bf16.h>

// Problem constants (reference: WORLD_SIZE=8, M_LOCAL=1024, K=4096, N=4096)
#define M_TOTAL 8192
#define KDIM    4096
#define NDIM    4096

#define TM 128
#define TN 128
#define BK 32

typedef __bf16 bf16x8 __attribute__((ext_vector_type(8)));
typedef float  f32x4  __attribute__((ext_vector_type(4)));

// ---------------------------------------------------------------------------
// fp32 -> bf16 (RNE), 8 elems/thread, 16B stores; A and W in one launch
// ---------------------------------------------------------------------------
__device__ __forceinline__ unsigned short f32_to_bf16_rne(unsigned u) {
    unsigned r = u + 0x7fffu + ((u >> 16) & 1u);
    return (unsigned short)(r >> 16);
}

__device__ __forceinline__ void cvt8(const float* __restrict__ s,
                                     unsigned short* __restrict__ d) {
    const uint4* sp = (const uint4*)s;
    uint4 x = sp[0];
    uint4 y = sp[1];
    uint4 o;
    o.x = (unsigned)f32_to_bf16_rne(x.x) | ((unsigned)f32_to_bf16_rne(x.y) << 16);
    o.y = (unsigned)f32_to_bf16_rne(x.z) | ((unsigned)f32_to_bf16_rne(x.w) << 16);
    o.z = (unsigned)f32_to_bf16_rne(y.x) | ((unsigned)f32_to_bf16_rne(y.y) << 16);
    o.w = (unsigned)f32_to_bf16_rne(y.z) | ((unsigned)f32_to_bf16_rne(y.w) << 16);
    *(uint4*)d = o;
}

__global__ __launch_bounds__(256) void cvt_both(const float* __restrict__ A,
                                                unsigned short* __restrict__ Abf,
                                                long nA,
                                                const float* __restrict__ W,
                                                unsigned short* __restrict__ Wbf) {
    long i = ((long)blockIdx.x * 256 + threadIdx.x) * 8;
    if (i < nA) {
        cvt8(A + i, Abf + i);
    } else {
        long j = i - nA;
        cvt8(W + j, Wbf + j);
    }
}

// ---------------------------------------------------------------------------
// async global -> LDS, 16B per lane (wave-uniform LDS base + lane*16)
// ---------------------------------------------------------------------------
__device__ __forceinline__ void gload_lds16(const unsigned short* g, unsigned short* l) {
    __builtin_amdgcn_global_load_lds(
        (const __attribute__((address_space(1))) unsigned int*)g,
        (__attribute__((address_space(3))) unsigned int*)l,
        16, 0, 0);
}

// ---------------------------------------------------------------------------
// C[M,N] = A[M,K] * B[N,K]^T   (bf16 inputs, fp32 out)
// 128x128 tile, BK=32, 256 threads (4 waves, 2x2), 16x16x32 bf16 MFMA.
//
// LDS K-chunk XOR swizzle (bank-conflict fix):
//   LDS slot (row, cs) holds global k-chunk  cs ^ ((row>>1)&3)   (16B chunks)
//   - staging: lane l (slot row=l>>2, cs=l&3) loads global chunk (l&3)^((l>>3)&3)
//   - reads:   global chunk `quad` of row r lives at slot  quad ^ ((r>>1)&3)
//   This spreads each 16-lane read phase across all 8 16B offsets per 128B
//   bank window -> 2 lanes/bank (free) instead of 8-way conflict.
// ---------------------------------------------------------------------------
__global__ __launch_bounds__(256) void gemm_bt(const unsigned short* __restrict__ A,
                                               const unsigned short* __restrict__ B,
                                               float* __restrict__ C) {
    __shared__ unsigned short lA[TM * BK];   // [128][32] shorts, 8 KiB
    __shared__ unsigned short lB[TN * BK];   // [128][32] shorts, 8 KiB

    const int tid  = threadIdx.x;
    const int wave = tid >> 6;
    const int lane = tid & 63;

    const int n0 = blockIdx.x * TN;
    const int m0 = blockIdx.y * TM;

    // staging: chunk c covers rows [c*16, c*16+16); lane l -> slot row l>>2
    const int row_ic = lane >> 2;                                  // 0..15
    const int kchunk = (lane & 3) ^ ((lane >> 3) & 3);             // swizzled src chunk
    const int k_ic   = kchunk * 8;                                 // element offset

    const int c0 = wave;
    const int c1 = wave + 4;

    const unsigned short* gA0 = A + (size_t)(m0 + c0 * 16 + row_ic) * KDIM + k_ic;
    const unsigned short* gA1 = A + (size_t)(m0 + c1 * 16 + row_ic) * KDIM + k_ic;
    const unsigned short* gB0 = B + (size_t)(n0 + c0 * 16 + row_ic) * KDIM + k_ic;
    const unsigned short* gB1 = B + (size_t)(n0 + c1 * 16 + row_ic) * KDIM + k_ic;
    unsigned short* lA0 = &lA[c0 * 16 * BK];   // wave-uniform LDS bases
    unsigned short* lA1 = &lA[c1 * 16 * BK];
    unsigned short* lB0 = &lB[c0 * 16 * BK];
    unsigned short* lB1 = &lB[c1 * 16 * BK];

    // wave -> 64x64 quadrant; MFMA fragment indices
    const int wm   = wave & 1;
    const int wn   = wave >> 1;
    const int quad = lane >> 4;    // 0..3  (K-chunk index for A/B operands)
    const int r    = lane & 15;    // m (A) / n (B) / col (C)

    const int sidx = (quad ^ ((r >> 1) & 3)) * 8;   // swizzled read offset (elems)

    f32x4 acc[4][4] = {};

    for (int k0 = 0; k0 < KDIM; k0 += BK) {
        gload_lds16(gA0 + k0, lA0);
        gload_lds16(gA1 + k0, lA1);
        gload_lds16(gB0 + k0, lB0);
        gload_lds16(gB1 + k0, lB1);
        __syncthreads();   // drains vmcnt -> staged data visible

        bf16x8 aF[4], bF[4];
#pragma unroll
        for (int mi = 0; mi < 4; ++mi)
            aF[mi] = *(const bf16x8*)&lA[(wm * 64 + mi * 16 + r) * BK + sidx];
#pragma unroll
        for (int ni = 0; ni < 4; ++ni)
            bF[ni] = *(const bf16x8*)&lB[(wn * 64 + ni * 16 + r) * BK + sidx];

#pragma unroll
        for (int mi = 0; mi < 4; ++mi)
#pragma unroll
            for (int ni = 0; ni < 4; ++ni)
                acc[mi][ni] = __builtin_amdgcn_mfma_f32_16x16x32_bf16(
                    aF[mi], bF[ni], acc[mi][ni], 0, 0, 0);

        __syncthreads();   // all reads done before next stage overwrites
    }

    // epilogue: C/D layout col = lane&15, row = quad*4 + reg  [verified m89/m91]
#pragma unroll
    for (int mi = 0; mi < 4; ++mi) {
        const int row = m0 + wm * 64 + mi * 16 + quad * 4;
#pragma unroll
        for (int ni = 0; ni < 4; ++ni) {
            const int col = n0 + wn * 64 + ni * 16 + r;
            float* p = C + (size_t)row * NDIM + col;
#pragma unroll
            for (int rr = 0; rr < 4; ++rr)
                p[(size_t)rr * NDIM] = acc[mi][ni][rr];
        }
    }
}

// ---------------------------------------------------------------------------
extern "C" void kernel_launch(void* const* d_in, const int* in_sizes, int n_in,
                              void* d_out, int out_size, void* d_ws, size_t ws_size,
                              hipStream_t stream) {
    const float* A = (const float*)d_in[0];   // [8,1024,4096] == [8192,4096]
    const float* W = (const float*)d_in[1];   // [4096,4096]  (N,K)
    float* out = (float*)d_out;               // [8192,4096] fp32

    unsigned short* Abf = (unsigned short*)d_ws;                       // 64 MiB
    unsigned short* Wbf = Abf + (size_t)M_TOTAL * KDIM;                // 32 MiB

    const long nA = (long)M_TOTAL * KDIM;     // 33,554,432
    const long nW = (long)NDIM * KDIM;        // 16,777,216
    const long nTot = nA + nW;

    cvt_both<<<(int)(nTot / 8 / 256), 256, 0, stream>>>(A, Abf, nA, W, Wbf);

    dim3 grid(NDIM / TN, M_TOTAL / TM);       // (32, 64) = 2048 blocks
    gemm_bt<<<grid, 256, 0, stream>>>(Abf, Wbf, out);
}